// Round 4
// baseline (232.862 us; speedup 1.0000x reference)
//
#include <hip/hip_runtime.h>

// Correlation layer, MAX_DISP=4: out[b, dx*9+dy, h, w] =
//   mean_c x1[b,c,h,w] * x2[b,c,h+dx-4,w+dy-4]  (x2 zero-padded)
// x1,x2: (8,64,256,256) fp32.  out: (8,81,256,256) fp32.
//
// R4: VW=8 split-wave. Lanes 0-31 handle row h (8 w each = 256), lanes
// 32-63 handle row h+1. Per channel per lane: 2 float4 of x1 + exactly
// 4 float4 of x2 (w0-4 .. w0+11, no halo waste) feed 72 FMAs ->
// 0.67 B/flop vs 0.89 before; total L1-return traffic 4.7 -> 3.5 GB.
// Prefetch-rotate channel loop, unroll 2 so rotation register-renames.
// 1-wave blocks + XCD swizzle (b = blockIdx&7) retained from R3.

namespace {
constexpr int kB = 8;
constexpr int kC = 64;
constexpr int kH = 256;
constexpr int kW = 256;
constexpr int kD = 9;          // 2*4+1
constexpr int kMD = 4;
constexpr int kChanStride = kH * kW;
}  // namespace

__global__ __launch_bounds__(64) void corr_kernel(
    const float* __restrict__ x1, const float* __restrict__ x2,
    float* __restrict__ out) {
  // XCD-locality decode (grid = 8 * 128 * 9, multiple of 8)
  const int xcd  = blockIdx.x & 7;
  const int slot = blockIdx.x >> 3;        // 0..1151, sequential on one XCD
  const int b  = xcd;
  const int hp = slot / kD;                // 0..127 (pair of rows)
  const int dx = slot - hp * kD;

  const int lane = (int)threadIdx.x;
  const int half = lane >> 5;              // 0: row h0, 1: row h0+1
  const int lh   = lane & 31;
  const int h    = hp * 2 + half;
  const int row  = h + dx - kMD;           // x2 source row (may be OOB)
  const int w0   = lh * 8;

  const bool rowok = (row >= 0) && (row < kH);
  const bool hasL  = rowok && (lh > 0);    // w0-4 .. w0-1 in bounds
  const bool hasR  = rowok && (lh < 31);   // w0+8 .. w0+11 in bounds

  float acc[kD][8];
#pragma unroll
  for (int dy = 0; dy < kD; ++dy)
#pragma unroll
    for (int j = 0; j < 8; ++j) acc[dy][j] = 0.0f;

  const float* p1 = x1 + ((size_t)(b * kC) * kH + h) * kW + w0;
  const float* p2 = x2 + ((size_t)(b * kC) * kH + row) * kW + w0;

  const float4 z = make_float4(0.f, 0.f, 0.f, 0.f);

  float4 a0, a1, t0, t1, t2, t3;
  // prologue: channel 0
  a0 = *reinterpret_cast<const float4*>(p1);
  a1 = *reinterpret_cast<const float4*>(p1 + 4);
  t0 = hasL  ? *reinterpret_cast<const float4*>(p2 - 4) : z;
  t1 = rowok ? *reinterpret_cast<const float4*>(p2)     : z;
  t2 = rowok ? *reinterpret_cast<const float4*>(p2 + 4) : z;
  t3 = hasR  ? *reinterpret_cast<const float4*>(p2 + 8) : z;

#pragma unroll 2
  for (int c = 0; c < kC - 1; ++c) {
    p1 += kChanStride;
    p2 += kChanStride;
    // prefetch next channel
    float4 na0 = *reinterpret_cast<const float4*>(p1);
    float4 na1 = *reinterpret_cast<const float4*>(p1 + 4);
    float4 nt0 = hasL  ? *reinterpret_cast<const float4*>(p2 - 4) : z;
    float4 nt1 = rowok ? *reinterpret_cast<const float4*>(p2)     : z;
    float4 nt2 = rowok ? *reinterpret_cast<const float4*>(p2 + 4) : z;
    float4 nt3 = hasR  ? *reinterpret_cast<const float4*>(p2 + 8) : z;

    {
      const float av[8] = {a0.x, a0.y, a0.z, a0.w, a1.x, a1.y, a1.z, a1.w};
      const float t[16] = {t0.x, t0.y, t0.z, t0.w, t1.x, t1.y, t1.z, t1.w,
                           t2.x, t2.y, t2.z, t2.w, t3.x, t3.y, t3.z, t3.w};
      // output col w0+j, shift dy: x2 col = w0+j+dy-4 -> t[j+dy] (t[0]=w0-4)
#pragma unroll
      for (int dy = 0; dy < kD; ++dy)
#pragma unroll
        for (int j = 0; j < 8; ++j)
          acc[dy][j] = fmaf(av[j], t[dy + j], acc[dy][j]);
    }

    a0 = na0; a1 = na1; t0 = nt0; t1 = nt1; t2 = nt2; t3 = nt3;
  }
  {  // epilogue: last channel
    const float av[8] = {a0.x, a0.y, a0.z, a0.w, a1.x, a1.y, a1.z, a1.w};
    const float t[16] = {t0.x, t0.y, t0.z, t0.w, t1.x, t1.y, t1.z, t1.w,
                         t2.x, t2.y, t2.z, t2.w, t3.x, t3.y, t3.z, t3.w};
#pragma unroll
    for (int dy = 0; dy < kD; ++dy)
#pragma unroll
      for (int j = 0; j < 8; ++j)
        acc[dy][j] = fmaf(av[j], t[dy + j], acc[dy][j]);
  }

  const float inv = 1.0f / (float)kC;
  float* po = out + (((size_t)b * (kD * kD) + dx * kD) * kH + h) * kW + w0;
#pragma unroll
  for (int dy = 0; dy < kD; ++dy) {
    float4 o0 = make_float4(acc[dy][0] * inv, acc[dy][1] * inv,
                            acc[dy][2] * inv, acc[dy][3] * inv);
    float4 o1 = make_float4(acc[dy][4] * inv, acc[dy][5] * inv,
                            acc[dy][6] * inv, acc[dy][7] * inv);
    *reinterpret_cast<float4*>(po)     = o0;
    *reinterpret_cast<float4*>(po + 4) = o1;
    po += (size_t)kH * kW;
  }
}

extern "C" void kernel_launch(void* const* d_in, const int* in_sizes, int n_in,
                              void* d_out, int out_size, void* d_ws, size_t ws_size,
                              hipStream_t stream) {
  const float* x1 = (const float*)d_in[0];
  const float* x2 = (const float*)d_in[1];
  float* out = (float*)d_out;
  const int grid = kB * (kH / 2) * kD;  // 9216 blocks, 1 wave each
  corr_kernel<<<grid, 64, 0, stream>>>(x1, x2, out);
}